// Round 1
// baseline (17.998 us; speedup 1.0000x reference)
//
#include <hip/hip_runtime.h>
#include <math.h>

static constexpr int Bb   = 16;
static constexpr int Ww   = 256;
static constexpr int HWp  = 256 * 256;   // 65536
static constexpr int CF   = 128;
static constexpr int Kk   = 2;
static constexpr int SEGS = 8;
static constexpr int SEGLEN = HWp / SEGS; // 8192

// Strict total order matching jax.lax.top_k: value descending, index ascending on ties.
__device__ __forceinline__ bool better(float v1, int i1, float v2, int i2) {
    return (v1 > v2) || ((v1 == v2) && (i1 < i2));
}

// Stage 1: per (row, seg) partial top-2 of softmax(infeat, axis=1) channel `c`.
// row = b*2 + c; 32 rows x SEGS segments.
__global__ __launch_bounds__(256) void top2_partial(
    const float* __restrict__ infeat, float* __restrict__ ws_v, int* __restrict__ ws_i)
{
    const int row = blockIdx.x;        // 0..31
    const int seg = blockIdx.y;        // 0..SEGS-1
    const int b = row >> 1, c = row & 1;
    const float* x0p = infeat + (size_t)(b * 2 + 0) * HWp;
    const float* x1p = infeat + (size_t)(b * 2 + 1) * HWp;
    const int t = threadIdx.x;

    float v0 = -INFINITY, v1 = -INFINITY;
    int   i0 = 0x7fffffff, i1 = 0x7fffffff;

    const int base = seg * SEGLEN + t * 4;
    #pragma unroll
    for (int it = 0; it < SEGLEN / (256 * 4); ++it) {
        const int p = base + it * (256 * 4);
        const float4 a  = *(const float4*)(x0p + p);
        const float4 bb = *(const float4*)(x1p + p);
        const float ax[4] = {a.x, a.y, a.z, a.w};
        const float bx[4] = {bb.x, bb.y, bb.z, bb.w};
        #pragma unroll
        for (int e = 0; e < 4; ++e) {
            const float m  = fmaxf(ax[e], bx[e]);
            const float e0 = expf(ax[e] - m);
            const float e1 = expf(bx[e] - m);
            const float v  = (c == 0 ? e0 : e1) / (e0 + e1);
            const int p2 = p + e;
            if (better(v, p2, v0, i0)) { v1 = v0; i1 = i0; v0 = v; i0 = p2; }
            else if (better(v, p2, v1, i1)) { v1 = v; i1 = p2; }
        }
    }

    __shared__ float sv[256][2];
    __shared__ int   si[256][2];
    sv[t][0] = v0; sv[t][1] = v1; si[t][0] = i0; si[t][1] = i1;
    __syncthreads();
    for (int s = 128; s > 0; s >>= 1) {
        if (t < s) {
            float a0 = sv[t][0], a1 = sv[t][1];
            int  ia0 = si[t][0], ia1 = si[t][1];
            float b0 = sv[t + s][0], b1 = sv[t + s][1];
            int  ib0 = si[t + s][0], ib1 = si[t + s][1];
            float r0, r1; int j0, j1;
            if (better(a0, ia0, b0, ib0)) {
                r0 = a0; j0 = ia0;
                if (better(b0, ib0, a1, ia1)) { r1 = b0; j1 = ib0; } else { r1 = a1; j1 = ia1; }
            } else {
                r0 = b0; j0 = ib0;
                if (better(a0, ia0, b1, ib1)) { r1 = a0; j1 = ia0; } else { r1 = b1; j1 = ib1; }
            }
            sv[t][0] = r0; sv[t][1] = r1; si[t][0] = j0; si[t][1] = j1;
        }
        __syncthreads();
    }
    if (t < 2) {
        ws_v[(row * SEGS + seg) * 2 + t] = sv[0][t];
        ws_i[(row * SEGS + seg) * 2 + t] = si[0][t];
    }
}

// Stage 2: one block per output point pi = c*B*k + b*k + j (64 points), 128 threads.
// Merge the SEGS partial top-2 lists of the row, take entry j, gather + write all outputs.
__global__ __launch_bounds__(128) void gather_out(
    const float* __restrict__ infeat,
    const float* __restrict__ labelTpesudo,
    const float* __restrict__ labelT,
    const float* __restrict__ FeatureDA,
    const float* __restrict__ ws_v, const int* __restrict__ ws_i,
    float* __restrict__ out)
{
    const int pi = blockIdx.x;           // 0..63
    const int c  = pi / (Bb * Kk);
    const int b  = (pi / Kk) % Bb;
    const int j  = pi % Kk;
    const int row = b * 2 + c;

    __shared__ float s_val;
    __shared__ int   s_idx;
    if (threadIdx.x == 0) {
        float bv0 = -INFINITY, bv1 = -INFINITY;
        int   bi0 = 0x7fffffff, bi1 = 0x7fffffff;
        for (int s2 = 0; s2 < SEGS; ++s2) {
            #pragma unroll
            for (int e = 0; e < 2; ++e) {
                const float v = ws_v[(row * SEGS + s2) * 2 + e];
                const int   i = ws_i[(row * SEGS + s2) * 2 + e];
                if (better(v, i, bv0, bi0)) { bv1 = bv0; bi1 = bi0; bv0 = v; bi0 = i; }
                else if (better(v, i, bv1, bi1)) { bv1 = v; bi1 = i; }
            }
        }
        s_val = (j == 0) ? bv0 : bv1;
        s_idx = (j == 0) ? bi0 : bi1;
    }
    __syncthreads();

    const int   idx = s_idx;
    const float val = s_val;
    const int py = idx >> 8;        // idx / W
    const int px = idx & (Ww - 1);  // idx % W
    const int t = threadIdx.x;

    // Output layout (flat float32, 8768 elems):
    //   [0,128)      classiferT   (64,2)
    //   [128,8320)   patchFeatDA  (64,128)
    //   [8320,8384)  labelTTrue   (64,1)
    //   [8384,8448)  labelpesudo  (64,1)
    //   [8448,8512)  provalue     (64,1)
    //   [8512,8768)  pointXY      (64,2,2) -> [px, min(px+31,255), py, min(py+31,255)]
    out[128 + pi * CF + t] = FeatureDA[((size_t)b * CF + t) * HWp + idx];
    if (t < 2) out[pi * 2 + t] = infeat[((size_t)b * 2 + t) * HWp + idx];
    if (t == 0) {
        out[8320 + pi] = labelT[(size_t)b * HWp + idx];
        out[8384 + pi] = labelTpesudo[(size_t)b * HWp + idx];
        out[8448 + pi] = val;
        out[8512 + pi * 4 + 0] = (float)px;
        out[8512 + pi * 4 + 1] = (float)min(px + 31, 255);
        out[8512 + pi * 4 + 2] = (float)py;
        out[8512 + pi * 4 + 3] = (float)min(py + 31, 255);
    }
}

extern "C" void kernel_launch(void* const* d_in, const int* in_sizes, int n_in,
                              void* d_out, int out_size, void* d_ws, size_t ws_size,
                              hipStream_t stream) {
    const float* infeat       = (const float*)d_in[0];
    const float* labelTpesudo = (const float*)d_in[1];
    const float* labelT       = (const float*)d_in[2];
    const float* FeatureDA    = (const float*)d_in[3];
    float* out = (float*)d_out;

    float* ws_v = (float*)d_ws;                                  // 32*SEGS*2 floats
    int*   ws_i = (int*)((char*)d_ws + 32 * SEGS * 2 * sizeof(float));

    dim3 g1(32, SEGS);
    top2_partial<<<g1, 256, 0, stream>>>(infeat, ws_v, ws_i);
    gather_out<<<64, 128, 0, stream>>>(infeat, labelTpesudo, labelT, FeatureDA,
                                       ws_v, ws_i, out);
}